// Round 13
// baseline (234.836 us; speedup 1.0000x reference)
//
#include <hip/hip_runtime.h>
#include <hip/hip_bf16.h>

// Problem constants (match reference)
#define NB 128          // graphs
#define NN 512          // nodes per graph
#define NF 128          // input/hidden feature dim
#define BN (NB*NN)      // 65536 total nodes
#define NE (BN*16)      // 1048576 edges
#define EPG 8192        // edges per graph (N*DEG_AVG)
#define WPR 16          // bitmap words per row (512 bits / 32)
#define ELLW 64         // ELL width (max padded degree)
#define QST 32          // poly w row stride in ushorts (64 B)
#define SST 72          // ELL staging stride (ushorts)
#define WTS 136         // gemm Wt LDS stride in ushorts (272 B, 16-B aligned)

typedef short sh8 __attribute__((ext_vector_type(8)));
typedef float f32x4 __attribute__((ext_vector_type(4)));

static __device__ __forceinline__ unsigned short f2bf(float f) {
    unsigned u = __float_as_uint(f);
    u += 0x7fffu + ((u >> 16) & 1u);        // round-to-nearest-even
    return (unsigned short)(u >> 16);
}

// acc += bf16_low(pk)  /  acc += bf16_high(pk) via VOP3P dot2 (exact).
#define DOT2LO(acc_, pk_, one_) \
    asm("v_dot2_f32_bf16 %0, %1, %2, %0" : "+v"(acc_) : "v"(pk_), "v"(one_))

// ---------------------------------------------------------------------------
// Fused build (R11, unchanged): 256 blocks (graph, RANK-HALF) x 1024 thr,
// 86,016 B LDS (prk aliased into els). Private full-graph LDS bitmap
// (atomicOr idempotent across the two half-blocks), then degree/rank/
// extract/writeout all from LDS. Outputs bit-identical to the original
// fused build (quartet + quarter-popc-prefix extraction order).
// ---------------------------------------------------------------------------
__global__ __launch_bounds__(1024) void build_fused_kernel(
    const int* __restrict__ src, const int* __restrict__ dst,
    unsigned short* __restrict__ ell, int* __restrict__ ocnt,
    float* __restrict__ dinvr, int* __restrict__ perm)
{
    __shared__ unsigned bm[NN * WPR];         // 32 KB full-graph bitmap
    __shared__ unsigned short els[256 * SST]; // 36,864 B staging (this half)
    __shared__ int qp[NN * 4];                // per-quarter popc (uncapped)
    __shared__ int cs[NN];                    // capped degree by row
    __shared__ int rdeg[NN];                  // degree by rank
    __shared__ int irank[NN];                 // row -> rank
    __shared__ int prow[NN];                  // rank -> row
    int* prk = (int*)els;                     // ALIAS: dead before els written
    int b = blockIdx.x;
    int g = b >> 1;
    int h = b & 1;                            // rank half: [h*256, h*256+256)
    int t = threadIdx.x;                      // 0..1023

    // ---- zero + scatter (all 8192 edges; idempotent across half-blocks)
    for (int i = t; i < NN * WPR; i += 1024) bm[i] = 0u;
    __syncthreads();

    const int4* sg4 = (const int4*)(src + (size_t)g * EPG);
    const int4* dg4 = (const int4*)(dst + (size_t)g * EPG);
    for (int i = t; i < EPG / 4; i += 1024) {
        int4 s4 = sg4[i];
        int4 d4 = dg4[i];
        int s, d;
        s = s4.x & (NN - 1); d = d4.x & (NN - 1);
        atomicOr(&bm[s * WPR + (d >> 5)], 1u << (d & 31));
        s = s4.y & (NN - 1); d = d4.y & (NN - 1);
        atomicOr(&bm[s * WPR + (d >> 5)], 1u << (d & 31));
        s = s4.z & (NN - 1); d = d4.z & (NN - 1);
        atomicOr(&bm[s * WPR + (d >> 5)], 1u << (d & 31));
        s = s4.w & (NN - 1); d = d4.w & (NN - 1);
        atomicOr(&bm[s * WPR + (d >> 5)], 1u << (d & 31));
    }
    __syncthreads();

    // ---- degree phase: 2 thr/row, each popcounts 2 quarters (from LDS)
    {
        int r = t & 511, hf = t >> 9;
        const unsigned* bgr = &bm[r * WPR + hf * 8];
        uint4 a = *(const uint4*)bgr;
        uint4 c = *(const uint4*)(bgr + 4);
        qp[r * 4 + hf * 2]     = __popc(a.x) + __popc(a.y) + __popc(a.z) + __popc(a.w);
        qp[r * 4 + hf * 2 + 1] = __popc(c.x) + __popc(c.y) + __popc(c.z) + __popc(c.w);
    }
    __syncthreads();
    if (t < NN) {
        int d = qp[t * 4] + qp[t * 4 + 1] + qp[t * 4 + 2] + qp[t * 4 + 3];
        cs[t] = (d > ELLW) ? ELLW : d;
    }
    __syncthreads();

    // ---- rank phase: ascending (deg, row); 2 thr/row scan half of cs each
    {
        int r = t & 511, hf = t >> 9;
        int deg_r = cs[r];
        const int4* c4 = (const int4*)cs;
        int ib = hf * 64;
        int pcnt = 0;
        #pragma unroll 8
        for (int ii = 0; ii < 64; ++ii) {
            int4 v = c4[ib + ii];
            int i0 = (ib + ii) * 4;
            pcnt += (v.x < deg_r) || (v.x == deg_r && (i0 + 0) < r);
            pcnt += (v.y < deg_r) || (v.y == deg_r && (i0 + 1) < r);
            pcnt += (v.z < deg_r) || (v.z == deg_r && (i0 + 2) < r);
            pcnt += (v.w < deg_r) || (v.w == deg_r && (i0 + 3) < r);
        }
        if (!hf) prk[r] = pcnt;
        __syncthreads();
        if (hf) {
            int rk = prk[r] + pcnt;
            irank[r] = rk;
            rdeg[rk] = deg_r;
            prow[rk] = r;
            if (h == 0) {
                perm[(size_t)g * NN + rk] = r;
                dinvr[(size_t)g * NN + rk] =
                    (deg_r > 0) ? rsqrtf((float)deg_r) : 0.0f;
            }
        }
    }
    __syncthreads();                          // irank/prow/rdeg visible;
                                              // prk dead from here on

    if (h == 0 && t < NN / 8) {
        int m = rdeg[t * 8 + 7];              // ascending: oct max = last
        ocnt[(size_t)g * (NN / 8) + t] = (m + 3) & ~3;
    }

    // ---- extraction: 4 thr per rank of this half; quartet member qw owns
    // bitmap words [4qw, 4qw+4). Start offset = prefix of quarter popcs ->
    // concatenated output order == original sequential order (bit-identical).
    {
        int rkl = t >> 2;                     // 0..255
        int qw  = t & 3;                      // quarter index
        int rk  = h * 256 + rkl;
        int row = prow[rk];
        uint4 bv = *(const uint4*)&bm[row * WPR + qw * 4];
        unsigned wbits[4] = {bv.x, bv.y, bv.z, bv.w};
        int c = 0;
        #pragma unroll
        for (int j = 0; j < 3; ++j) c += (j < qw) ? qp[row * 4 + j] : 0;
        unsigned short* er = &els[rkl * SST];
        #pragma unroll
        for (int w = 0; w < 4; ++w) {
            unsigned bits = wbits[w];
            while (bits) {
                int j = __ffs(bits) - 1;
                bits &= bits - 1;
                if (c < ELLW) er[c] = (unsigned short)irank[(qw * 4 + w) * 32 + j];
                ++c;
            }
        }
        if (qw == 3) {                        // c now == total (uncapped)
            int cc = (c > ELLW) ? ELLW : c;
            for (int p = cc; p < ELLW; ++p) er[p] = (unsigned short)NN;
        }
    }
    __syncthreads();                          // staging complete

    // ---- writeout: 256 rows x 128 B = 32 KB, 2 uint4 per thread
    unsigned short* outb = ell + ((size_t)g * NN + (size_t)h * 256) * ELLW;
    for (int idx = t; idx < 256 * 8; idx += 1024) {
        int r2 = idx >> 3, sg2 = idx & 7;
        uint4 v = *(const uint4*)&els[r2 * SST + sg2 * 8];
        *(uint4*)&outb[(size_t)r2 * ELLW + sg2 * 8] = v;
    }
}

// ---------------------------------------------------------------------------
// One hop of the poly conv: gather from wsrc, fold into acc, optionally
// pack+write to wdst (the last hop's write is dead -> DOWR=false skips it).
// ---------------------------------------------------------------------------
template<bool DOWR>
static __device__ __forceinline__ void hop_pass(
    const unsigned short* __restrict__ wsrc,
    unsigned short* __restrict__ wdst,
    const unsigned short* __restrict__ ellg,   // ell + g*NN*ELLW
    const int (&rnk)[4], const int (&co)[4], const float (&di)[4],
    int fbq, float (&acc)[4][8], unsigned one_lo, unsigned one_hi)
{
    #pragma unroll
    for (int x = 0; x < 4; ++x) {
        const unsigned short* el = ellg + (size_t)rnk[x] * ELLW;
        int cnt = co[x];
        float s[8];
        #pragma unroll
        for (int k = 0; k < 8; ++k) s[k] = 0.0f;

        ushort4 cur = *(const ushort4*)el;       // quad-uniform load
        for (int p = 0; p < cnt; p += 4) {
            ushort4 nxt = cur;
            if (p + 4 < cnt) nxt = *(const ushort4*)(el + p + 4);
            uint4 v0 = *(const uint4*)&wsrc[(int)cur.x * QST + fbq * 8];
            uint4 v1 = *(const uint4*)&wsrc[(int)cur.y * QST + fbq * 8];
            uint4 v2 = *(const uint4*)&wsrc[(int)cur.z * QST + fbq * 8];
            uint4 v3 = *(const uint4*)&wsrc[(int)cur.w * QST + fbq * 8];
            unsigned d[4][4] = {{v0.x, v0.y, v0.z, v0.w},
                                {v1.x, v1.y, v1.z, v1.w},
                                {v2.x, v2.y, v2.z, v2.w},
                                {v3.x, v3.y, v3.z, v3.w}};
            #pragma unroll
            for (int n = 0; n < 4; ++n) {
                #pragma unroll
                for (int k = 0; k < 4; ++k) {
                    DOT2LO(s[2 * k],     d[n][k], one_lo);
                    DOT2LO(s[2 * k + 1], d[n][k], one_hi);
                }
            }
            cur = nxt;
        }

        float dx = di[x];
        unsigned pk[4];
        #pragma unroll
        for (int k = 0; k < 4; ++k) {
            float zlo = dx * s[2 * k];
            float zhi = dx * s[2 * k + 1];
            acc[x][2 * k]     += zlo;
            acc[x][2 * k + 1] += zhi;
            if (DOWR) {
                unsigned lo = (unsigned)f2bf(dx * zlo);
                unsigned hi = (unsigned)f2bf(dx * zhi);
                pk[k] = lo | (hi << 16);
            }
        }
        if (DOWR)
            *(uint4*)&wdst[rnk[x] * QST + fbq * 8] =
                make_uint4(pk[0], pk[1], pk[2], pk[3]);
    }
}

// ---------------------------------------------------------------------------
// Fused 3-hop poly conv in RANK space, one block per (graph, feature-QUARTER).
// grid = 512 blocks of 512 thr. R13: DOUBLE-BUFFERED w (65.7 KB LDS,
// 2 blocks/CU) — hop h reads buffer A and writes B, so the read-barrier and
// write-barrier collapse to ONE barrier per hop; hop 2's w write (dead —
// output comes from registers) is skipped; dsh LDS array deleted (each
// thread only ever used its own 4 values -> 4 regs loaded from dinvr).
// Barriers per block: 8 -> 3. All removed work dead or value-identical ->
// bitwise-identical output. R5 bank layout + R7 bf16 accout retained.
// ---------------------------------------------------------------------------
__global__ __launch_bounds__(512, 4) void poly_fused_kernel(
    const float* __restrict__ xin,            // [BN, NF] f32
    unsigned short* __restrict__ accout,      // [BN, NF] bf16, rank space
    const unsigned short* __restrict__ ell,   // [BN][ELLW] rank entries
    const int* __restrict__ ocnt,             // [BN/8] padded oct counts
    const float* __restrict__ dinvr,          // [BN] rank-indexed
    const int* __restrict__ perm,             // [BN] rank -> row
    int permuteIn)
{
    extern __shared__ float lds[];
    unsigned short* wA = (unsigned short*)lds;       // (NN+1) rows * QST
    unsigned short* wB = wA + (NN + 1) * QST;        // second buffer

    int b = blockIdx.x;
    int g = b & 127;                     // graph (same-graph blocks -> same XCD)
    int q = b >> 7;                      // feature quarter (32 feats)
    int t = threadIdx.x;                 // 0..511
    int wid = t >> 6;                    // 0..7
    int qd  = (t >> 2) & 15;             // quad-in-wave 0..15
    int fbq = t & 3;                     // 16-B chunk 0..3 (8 feats)

    unsigned one_lo = 0x00003F80u;       // bf16x2 (1.0, 0.0)
    unsigned one_hi = 0x3F800000u;       // bf16x2 (0.0, 1.0)

    if (t < QST) {                       // zero sentinel rows (bf16 0)
        wA[NN * QST + t] = 0;
        wB[NN * QST + t] = 0;
    }

    // 4 passes of 128 ranks; wave handles 16 consecutive ranks (= 2 octs)
    // per pass. Passes 2,3 flip wave order for load balance.
    int rnk[4];
    #pragma unroll
    for (int x = 0; x < 4; ++x) {
        int wl = (x >= 2) ? (7 - wid) : wid;
        rnk[x] = x * 128 + wl * 16 + qd;
    }

    // wave-uniform padded counts: the wave's 16 ranks span octs ob, ob+1
    const int* oc = ocnt + (size_t)g * (NN / 8);
    int co[4];
    #pragma unroll
    for (int x = 0; x < 4; ++x) {
        int ob = (rnk[x] - qd) >> 3;
        co[x] = __builtin_amdgcn_readfirstlane(max(oc[ob], oc[ob + 1]));
    }

    // per-rank dinv in registers (each thread only needs its own 4 values)
    float di[4];
    {
        const float* dg = dinvr + (size_t)g * NN;
        #pragma unroll
        for (int x = 0; x < 4; ++x) di[x] = dg[rnk[x]];
    }

    // input row per pass: perm'd for layer 1, identity (coalesced) else
    int px[4];
    if (permuteIn) {
        const int* pmg = perm + (size_t)g * NN;
        #pragma unroll
        for (int x = 0; x < 4; ++x) px[x] = pmg[rnk[x]];
    } else {
        #pragma unroll
        for (int x = 0; x < 4; ++x) px[x] = rnk[x];
    }

    const float* xg = xin + (size_t)g * NN * NF + q * 32 + fbq * 8;

    float acc[4][8];
    #pragma unroll
    for (int x = 0; x < 4; ++x) {
        int row = px[x];
        float4 a0 = *(const float4*)&xg[(size_t)row * NF];
        float4 a1 = *(const float4*)&xg[(size_t)row * NF + 4];
        acc[x][0] = a0.x; acc[x][1] = a0.y; acc[x][2] = a0.z; acc[x][3] = a0.w;
        acc[x][4] = a1.x; acc[x][5] = a1.y; acc[x][6] = a1.z; acc[x][7] = a1.w;
    }

    // initial pack into wA (same rounding chain as before: f2bf(di*acc))
    #pragma unroll
    for (int x = 0; x < 4; ++x) {
        float dx = di[x];
        unsigned pk[4];
        #pragma unroll
        for (int k = 0; k < 4; ++k) {
            unsigned lo = (unsigned)f2bf(dx * acc[x][2 * k]);
            unsigned hi = (unsigned)f2bf(dx * acc[x][2 * k + 1]);
            pk[k] = lo | (hi << 16);
        }
        *(uint4*)&wA[rnk[x] * QST + fbq * 8] = make_uint4(pk[0], pk[1], pk[2], pk[3]);
    }
    __syncthreads();                     // wA + sentinels ready

    const unsigned short* ellg = ell + (size_t)g * NN * ELLW;

    // hop 0: read A, write B
    hop_pass<true >(wA, wB, ellg, rnk, co, di, fbq, acc, one_lo, one_hi);
    __syncthreads();                     // wB complete; wA reads done
    // hop 1: read B, write A
    hop_pass<true >(wB, wA, ellg, rnk, co, di, fbq, acc, one_lo, one_hi);
    __syncthreads();                     // wA complete; wB reads done
    // hop 2: read A; w write is dead (output comes from acc)
    hop_pass<false>(wA, wB, ellg, rnk, co, di, fbq, acc, one_lo, one_hi);

    // coalesced bf16 write at rank positions (16 B per pass per thread)
    unsigned short* og = accout + (size_t)g * NN * NF + q * 32 + fbq * 8;
    #pragma unroll
    for (int x = 0; x < 4; ++x) {
        int rr = rnk[x];
        uint4 pk;
        pk.x = (unsigned)f2bf(acc[x][0]) | ((unsigned)f2bf(acc[x][1]) << 16);
        pk.y = (unsigned)f2bf(acc[x][2]) | ((unsigned)f2bf(acc[x][3]) << 16);
        pk.z = (unsigned)f2bf(acc[x][4]) | ((unsigned)f2bf(acc[x][5]) << 16);
        pk.w = (unsigned)f2bf(acc[x][6]) | ((unsigned)f2bf(acc[x][7]) << 16);
        *(uint4*)&og[(size_t)rr * NF] = pk;
    }
}

// ---------------------------------------------------------------------------
// MFMA bf16 GEMM: Y[65536,128] = relu(bf16X @ bf16(W) + b), optional fused
// deterministic mean-pool partials. (unchanged: bf16 X input, fuse=1 skips
// the dead Y store.)
// ---------------------------------------------------------------------------
__global__ __launch_bounds__(256, 2) void gemm_bias_relu_kernel(
    const unsigned short* __restrict__ X,   // [BN, NF] bf16
    const float* __restrict__ W,
    const float* __restrict__ b, float* __restrict__ Y,
    float* __restrict__ partial, int fuse)
{
    __shared__ __align__(16) unsigned short Wt[NF * WTS];  // [n][k] bf16
    __shared__ float part[4 * NF];

    int t = threadIdx.x;

    // stage Wt = W^T in bf16
    for (int i = t; i < NF * NF / 4; i += 256) {
        int k = i >> 5;                 // W row
        int n4 = (i & 31) * 4;          // W col group
        float4 wv = ((const float4*)W)[i];
        Wt[(n4 + 0) * WTS + k] = f2bf(wv.x);
        Wt[(n4 + 1) * WTS + k] = f2bf(wv.y);
        Wt[(n4 + 2) * WTS + k] = f2bf(wv.z);
        Wt[(n4 + 3) * WTS + k] = f2bf(wv.w);
    }
    __syncthreads();

    int lane = t & 63;
    int wid  = t >> 6;                  // 0..3
    int quad = lane >> 4;               // 0..3
    int l16  = lane & 15;
    int rowA0 = blockIdx.x * 128 + wid * 32;

    // A fragments: direct bf16 16-B loads (no conversion chain)
    union { uint4 q; sh8 v; } af[2][4];
    #pragma unroll
    for (int m = 0; m < 2; ++m) {
        int r = rowA0 + m * 16 + l16;
        const unsigned short* xr = X + (size_t)r * NF + quad * 8;
        #pragma unroll
        for (int kk = 0; kk < 4; ++kk)
            af[m][kk].q = *(const uint4*)(xr + kk * 32);
    }

    f32x4 acc[2][8];
    #pragma unroll
    for (int m = 0; m < 2; ++m)
        #pragma unroll
        for (int c = 0; c < 8; ++c) acc[m][c] = (f32x4){0.f, 0.f, 0.f, 0.f};

    #pragma unroll
    for (int c = 0; c < 8; ++c) {
        const unsigned short* wb = &Wt[(c * 16 + l16) * WTS + quad * 8];
        #pragma unroll
        for (int kk = 0; kk < 4; ++kk) {
            union { uint4 q; sh8 v; } bf_;
            bf_.q = *(const uint4*)(wb + kk * 32);
            acc[0][c] = __builtin_amdgcn_mfma_f32_16x16x32_bf16(
                af[0][kk].v, bf_.v, acc[0][c], 0, 0, 0);
            acc[1][c] = __builtin_amdgcn_mfma_f32_16x16x32_bf16(
                af[1][kk].v, bf_.v, acc[1][c], 0, 0, 0);
        }
    }

    float psum[8];
    #pragma unroll
    for (int c = 0; c < 8; ++c) psum[c] = 0.0f;

    #pragma unroll
    for (int c = 0; c < 8; ++c) {
        int col = c * 16 + l16;
        float bias = b[col];
        #pragma unroll
        for (int m = 0; m < 2; ++m) {
            #pragma unroll
            for (int reg = 0; reg < 4; ++reg) {
                int r = rowA0 + m * 16 + quad * 4 + reg;
                float v = fmaxf(acc[m][c][reg] + bias, 0.0f);
                if (!fuse) Y[(size_t)r * NF + col] = v;
                psum[c] += v;
            }
        }
    }

    if (fuse) {
        // deterministic cross-quad reduction, then cross-wave LDS tree
        #pragma unroll
        for (int c = 0; c < 8; ++c) {
            float v = psum[c];
            v += __shfl_xor(v, 16);
            v += __shfl_xor(v, 32);
            if (lane < 16) part[wid * NF + c * 16 + lane] = v;
        }
        __syncthreads();
        if (t < NF) {
            float s = part[t] + part[NF + t] + part[2 * NF + t]
                    + part[3 * NF + t];
            partial[(size_t)blockIdx.x * NF + t] = s;
        }
    }
}

// ---------------------------------------------------------------------------
// Readout: per graph, mean-pool from gemm2 partials (4 blocks/graph) + MLP.
// ---------------------------------------------------------------------------
__global__ __launch_bounds__(128) void readout_kernel(
    const float* __restrict__ partial,   // [BN/128][NF]
    const float* __restrict__ Wr1, const float* __restrict__ br1,
    const float* __restrict__ Wr2, const float* __restrict__ br2,
    float* __restrict__ out)
{
    __shared__ float hsh[NF];
    __shared__ float r1[64];

    int g = blockIdx.x;
    int t = threadIdx.x;

    const float* pg = partial + (size_t)g * 4 * NF;
    float s = 0.0f;
    #pragma unroll
    for (int j = 0; j < 4; ++j) s += pg[j * NF + t];
    hsh[t] = s * (1.0f / (float)NN);
    __syncthreads();

    if (t < 64) {
        float a = br1[t];
        #pragma unroll 8
        for (int k = 0; k < NF; ++k) a += hsh[k] * Wr1[k * 64 + t];
        r1[t] = fmaxf(a, 0.0f);
    }
    __syncthreads();

    if (t < 64) {
        float v = r1[t] * Wr2[t];
        #pragma unroll
        for (int off = 32; off; off >>= 1) v += __shfl_down(v, off);
        if (t == 0) out[g] = v + br2[0];
    }
}

// ---------------------------------------------------------------------------
extern "C" void kernel_launch(void* const* d_in, const int* in_sizes, int n_in,
                              void* d_out, int out_size, void* d_ws, size_t ws_size,
                              hipStream_t stream)
{
    const float* X    = (const float*)d_in[0];
    // d_in[1] = batch (unused; nodes already grouped per graph)
    const int*   ei   = (const int*)d_in[2];
    const float* W1   = (const float*)d_in[3];
    const float* b1   = (const float*)d_in[4];
    const float* W2   = (const float*)d_in[5];
    const float* b2   = (const float*)d_in[6];
    const float* Wr1  = (const float*)d_in[7];
    const float* br1  = (const float*)d_in[8];
    const float* Wr2  = (const float*)d_in[9];
    const float* br2  = (const float*)d_in[10];
    float* out = (float*)d_out;

    const int* src = ei;
    const int* dst = ei + NE;

    // workspace layout
    char* ws = (char*)d_ws;
    float*          dinvr   = (float*)(ws);                          // 256 KB
    int*            ocnt    = (int*)(ws + (size_t)256 * 1024);       // 32 KB
    int*            perm    = (int*)(ws + (size_t)512 * 1024);       // 256 KB
    float*          partial = (float*)(ws + (size_t)768 * 1024);     // 256 KB
    unsigned short* ell     = (unsigned short*)(ws + (size_t)1024 * 1024); // 8 MB
    unsigned short* buf0    = (unsigned short*)(ws + (size_t)16384 * 1024); // 16.7 MB bf16
    float*          buf1    = (float*)(ws + (size_t)49152 * 1024);   // 32 MB f32

    // ---- adjacency build: single fused kernel (graph x rank-half)
    build_fused_kernel<<<NB * 2, 1024, 0, stream>>>(src, dst, ell, ocnt,
                                                    dinvr, perm);

    // double-buffered bf16 w rows: 2 * 513 * 64 B = 65,664 B
    const size_t LDSSZ = (size_t)2 * (NN + 1) * QST * 2;

    // ---- Layer 1 (X gathered via perm into rank space; accout bf16)
    poly_fused_kernel<<<NB * 4, 512, LDSSZ, stream>>>(X, buf0, ell, ocnt,
                                                      dinvr, perm, 1);
    gemm_bias_relu_kernel<<<BN / 128, 256, 0, stream>>>(buf0, W1, b1, buf1,
                                                        partial, 0);

    // ---- Layer 2 (all rank space, fully coalesced; accout bf16)
    poly_fused_kernel<<<NB * 4, 512, LDSSZ, stream>>>(buf1, buf0, ell, ocnt,
                                                      dinvr, perm, 0);
    gemm_bias_relu_kernel<<<BN / 128, 256, 0, stream>>>(buf0, W2, b2, buf1,
                                                        partial, 1);

    // ---- Readout from partials
    readout_kernel<<<NB, 128, 0, stream>>>(partial, Wr1, br1, Wr2, br2, out);
}

// Round 15
// 213.380 us; speedup vs baseline: 1.1006x; 1.1006x over previous
//
#include <hip/hip_runtime.h>
#include <hip/hip_bf16.h>

// Problem constants (match reference)
#define NB 128          // graphs
#define NN 512          // nodes per graph
#define NF 128          // input/hidden feature dim
#define BN (NB*NN)      // 65536 total nodes
#define NE (BN*16)      // 1048576 edges
#define EPG 8192        // edges per graph (N*DEG_AVG)
#define WPR 16          // bitmap words per row (512 bits / 32)
#define ELLW 64         // ELL width (max padded degree)
#define QST 32          // poly w row stride in ushorts (64 B)
#define SST 72          // ELL staging stride (ushorts)
#define WTS 136         // gemm Wt LDS stride in ushorts (272 B, 16-B aligned)

typedef short sh8 __attribute__((ext_vector_type(8)));
typedef float f32x4 __attribute__((ext_vector_type(4)));

static __device__ __forceinline__ unsigned short f2bf(float f) {
    unsigned u = __float_as_uint(f);
    u += 0x7fffu + ((u >> 16) & 1u);        // round-to-nearest-even
    return (unsigned short)(u >> 16);
}

// acc += bf16_low(pk)  /  acc += bf16_high(pk) via VOP3P dot2 (exact).
#define DOT2LO(acc_, pk_, one_) \
    asm("v_dot2_f32_bf16 %0, %1, %2, %0" : "+v"(acc_) : "v"(pk_), "v"(one_))

// ---------------------------------------------------------------------------
// Fused build (R11, unchanged): 256 blocks (graph, RANK-HALF) x 1024 thr,
// 86,016 B LDS (prk aliased into els). Private full-graph LDS bitmap
// (atomicOr idempotent across the two half-blocks), then degree/rank/
// extract/writeout all from LDS. Outputs bit-identical to the original
// fused build (quartet + quarter-popc-prefix extraction order).
// ---------------------------------------------------------------------------
__global__ __launch_bounds__(1024) void build_fused_kernel(
    const int* __restrict__ src, const int* __restrict__ dst,
    unsigned short* __restrict__ ell, int* __restrict__ ocnt,
    float* __restrict__ dinvr, int* __restrict__ perm)
{
    __shared__ unsigned bm[NN * WPR];         // 32 KB full-graph bitmap
    __shared__ unsigned short els[256 * SST]; // 36,864 B staging (this half)
    __shared__ int qp[NN * 4];                // per-quarter popc (uncapped)
    __shared__ int cs[NN];                    // capped degree by row
    __shared__ int rdeg[NN];                  // degree by rank
    __shared__ int irank[NN];                 // row -> rank
    __shared__ int prow[NN];                  // rank -> row
    int* prk = (int*)els;                     // ALIAS: dead before els written
    int b = blockIdx.x;
    int g = b >> 1;
    int h = b & 1;                            // rank half: [h*256, h*256+256)
    int t = threadIdx.x;                      // 0..1023

    // ---- zero + scatter (all 8192 edges; idempotent across half-blocks)
    for (int i = t; i < NN * WPR; i += 1024) bm[i] = 0u;
    __syncthreads();

    const int4* sg4 = (const int4*)(src + (size_t)g * EPG);
    const int4* dg4 = (const int4*)(dst + (size_t)g * EPG);
    for (int i = t; i < EPG / 4; i += 1024) {
        int4 s4 = sg4[i];
        int4 d4 = dg4[i];
        int s, d;
        s = s4.x & (NN - 1); d = d4.x & (NN - 1);
        atomicOr(&bm[s * WPR + (d >> 5)], 1u << (d & 31));
        s = s4.y & (NN - 1); d = d4.y & (NN - 1);
        atomicOr(&bm[s * WPR + (d >> 5)], 1u << (d & 31));
        s = s4.z & (NN - 1); d = d4.z & (NN - 1);
        atomicOr(&bm[s * WPR + (d >> 5)], 1u << (d & 31));
        s = s4.w & (NN - 1); d = d4.w & (NN - 1);
        atomicOr(&bm[s * WPR + (d >> 5)], 1u << (d & 31));
    }
    __syncthreads();

    // ---- degree phase: 2 thr/row, each popcounts 2 quarters (from LDS)
    {
        int r = t & 511, hf = t >> 9;
        const unsigned* bgr = &bm[r * WPR + hf * 8];
        uint4 a = *(const uint4*)bgr;
        uint4 c = *(const uint4*)(bgr + 4);
        qp[r * 4 + hf * 2]     = __popc(a.x) + __popc(a.y) + __popc(a.z) + __popc(a.w);
        qp[r * 4 + hf * 2 + 1] = __popc(c.x) + __popc(c.y) + __popc(c.z) + __popc(c.w);
    }
    __syncthreads();
    if (t < NN) {
        int d = qp[t * 4] + qp[t * 4 + 1] + qp[t * 4 + 2] + qp[t * 4 + 3];
        cs[t] = (d > ELLW) ? ELLW : d;
    }
    __syncthreads();

    // ---- rank phase: ascending (deg, row); 2 thr/row scan half of cs each
    {
        int r = t & 511, hf = t >> 9;
        int deg_r = cs[r];
        const int4* c4 = (const int4*)cs;
        int ib = hf * 64;
        int pcnt = 0;
        #pragma unroll 8
        for (int ii = 0; ii < 64; ++ii) {
            int4 v = c4[ib + ii];
            int i0 = (ib + ii) * 4;
            pcnt += (v.x < deg_r) || (v.x == deg_r && (i0 + 0) < r);
            pcnt += (v.y < deg_r) || (v.y == deg_r && (i0 + 1) < r);
            pcnt += (v.z < deg_r) || (v.z == deg_r && (i0 + 2) < r);
            pcnt += (v.w < deg_r) || (v.w == deg_r && (i0 + 3) < r);
        }
        if (!hf) prk[r] = pcnt;
        __syncthreads();
        if (hf) {
            int rk = prk[r] + pcnt;
            irank[r] = rk;
            rdeg[rk] = deg_r;
            prow[rk] = r;
            if (h == 0) {
                perm[(size_t)g * NN + rk] = r;
                dinvr[(size_t)g * NN + rk] =
                    (deg_r > 0) ? rsqrtf((float)deg_r) : 0.0f;
            }
        }
    }
    __syncthreads();                          // irank/prow/rdeg visible;
                                              // prk dead from here on

    if (h == 0 && t < NN / 8) {
        int m = rdeg[t * 8 + 7];              // ascending: oct max = last
        ocnt[(size_t)g * (NN / 8) + t] = (m + 3) & ~3;
    }

    // ---- extraction: 4 thr per rank of this half; quartet member qw owns
    // bitmap words [4qw, 4qw+4). Start offset = prefix of quarter popcs ->
    // concatenated output order == original sequential order (bit-identical).
    {
        int rkl = t >> 2;                     // 0..255
        int qw  = t & 3;                      // quarter index
        int rk  = h * 256 + rkl;
        int row = prow[rk];
        uint4 bv = *(const uint4*)&bm[row * WPR + qw * 4];
        unsigned wbits[4] = {bv.x, bv.y, bv.z, bv.w};
        int c = 0;
        #pragma unroll
        for (int j = 0; j < 3; ++j) c += (j < qw) ? qp[row * 4 + j] : 0;
        unsigned short* er = &els[rkl * SST];
        #pragma unroll
        for (int w = 0; w < 4; ++w) {
            unsigned bits = wbits[w];
            while (bits) {
                int j = __ffs(bits) - 1;
                bits &= bits - 1;
                if (c < ELLW) er[c] = (unsigned short)irank[(qw * 4 + w) * 32 + j];
                ++c;
            }
        }
        if (qw == 3) {                        // c now == total (uncapped)
            int cc = (c > ELLW) ? ELLW : c;
            for (int p = cc; p < ELLW; ++p) er[p] = (unsigned short)NN;
        }
    }
    __syncthreads();                          // staging complete

    // ---- writeout: 256 rows x 128 B = 32 KB, 2 uint4 per thread
    unsigned short* outb = ell + ((size_t)g * NN + (size_t)h * 256) * ELLW;
    for (int idx = t; idx < 256 * 8; idx += 1024) {
        int r2 = idx >> 3, sg2 = idx & 7;
        uint4 v = *(const uint4*)&els[r2 * SST + sg2 * 8];
        *(uint4*)&outb[(size_t)r2 * ELLW + sg2 * 8] = v;
    }
}

// ---------------------------------------------------------------------------
// Fused 3-hop poly conv in RANK space, one block per (graph, feature-QUARTER).
// grid = 512 blocks of 512 thr, 32.8 KB LDS. R15 == R14 source (unmodified
// resubmit — R14's bench died with a broker-side "container failed twice";
// both component kernels are R11/R12-verified shapes). Structure = R11 poly
// (measured 41.8us) with dsh LDS array replaced by 4 per-thread registers
// loaded from dinvr (identical values/order -> bit-identical output).
// ---------------------------------------------------------------------------
__global__ __launch_bounds__(512, 4) void poly_fused_kernel(
    const float* __restrict__ xin,            // [BN, NF] f32
    unsigned short* __restrict__ accout,      // [BN, NF] bf16, rank space
    const unsigned short* __restrict__ ell,   // [BN][ELLW] rank entries
    const int* __restrict__ ocnt,             // [BN/8] padded oct counts
    const float* __restrict__ dinvr,          // [BN] rank-indexed
    const int* __restrict__ perm,             // [BN] rank -> row
    int permuteIn)
{
    extern __shared__ float lds[];
    unsigned short* w = (unsigned short*)lds;        // (NN+1) rows * QST

    int b = blockIdx.x;
    int g = b & 127;                     // graph (same-graph blocks -> same XCD)
    int q = b >> 7;                      // feature quarter (32 feats)
    int t = threadIdx.x;                 // 0..511
    int wid = t >> 6;                    // 0..7
    int qd  = (t >> 2) & 15;             // quad-in-wave 0..15
    int fbq = t & 3;                     // 16-B chunk 0..3 (8 feats)

    unsigned one_lo = 0x00003F80u;       // bf16x2 (1.0, 0.0)
    unsigned one_hi = 0x3F800000u;       // bf16x2 (0.0, 1.0)

    if (t < QST) w[NN * QST + t] = 0;    // zero sentinel row (bf16 0)

    // 4 passes of 128 ranks; wave handles 16 consecutive ranks (= 2 octs)
    // per pass. Passes 2,3 flip wave order for load balance.
    int rnk[4];
    #pragma unroll
    for (int x = 0; x < 4; ++x) {
        int wl = (x >= 2) ? (7 - wid) : wid;
        rnk[x] = x * 128 + wl * 16 + qd;
    }

    // wave-uniform padded counts: the wave's 16 ranks span octs ob, ob+1
    const int* oc = ocnt + (size_t)g * (NN / 8);
    int co[4];
    #pragma unroll
    for (int x = 0; x < 4; ++x) {
        int ob = (rnk[x] - qd) >> 3;
        co[x] = __builtin_amdgcn_readfirstlane(max(oc[ob], oc[ob + 1]));
    }

    // per-rank dinv in registers (each thread only needs its own 4 values)
    float di[4];
    {
        const float* dg = dinvr + (size_t)g * NN;
        #pragma unroll
        for (int x = 0; x < 4; ++x) di[x] = dg[rnk[x]];
    }

    // input row per pass: perm'd for layer 1, identity (coalesced) else
    int px[4];
    if (permuteIn) {
        const int* pmg = perm + (size_t)g * NN;
        #pragma unroll
        for (int x = 0; x < 4; ++x) px[x] = pmg[rnk[x]];
    } else {
        #pragma unroll
        for (int x = 0; x < 4; ++x) px[x] = rnk[x];
    }

    const float* xg = xin + (size_t)g * NN * NF + q * 32 + fbq * 8;

    float acc[4][8];
    #pragma unroll
    for (int x = 0; x < 4; ++x) {
        int row = px[x];
        float4 a0 = *(const float4*)&xg[(size_t)row * NF];
        float4 a1 = *(const float4*)&xg[(size_t)row * NF + 4];
        acc[x][0] = a0.x; acc[x][1] = a0.y; acc[x][2] = a0.z; acc[x][3] = a0.w;
        acc[x][4] = a1.x; acc[x][5] = a1.y; acc[x][6] = a1.z; acc[x][7] = a1.w;
    }

    __syncthreads();                     // sentinel ready

    #pragma unroll
    for (int x = 0; x < 4; ++x) {
        float dx = di[x];
        unsigned pk[4];
        #pragma unroll
        for (int k = 0; k < 4; ++k) {
            unsigned lo = (unsigned)f2bf(dx * acc[x][2 * k]);
            unsigned hi = (unsigned)f2bf(dx * acc[x][2 * k + 1]);
            pk[k] = lo | (hi << 16);
        }
        *(uint4*)&w[rnk[x] * QST + fbq * 8] = make_uint4(pk[0], pk[1], pk[2], pk[3]);
    }
    __syncthreads();                     // w init ready

    for (int hop = 0; hop < 3; ++hop) {
        unsigned pst[4][4];              // staged bf16x2 packs per pass
        #pragma unroll
        for (int x = 0; x < 4; ++x) {
            const unsigned short* el =
                ell + ((size_t)g * NN + rnk[x]) * ELLW;
            int cnt = co[x];
            float s[8];
            #pragma unroll
            for (int k = 0; k < 8; ++k) s[k] = 0.0f;

            ushort4 cur = *(const ushort4*)el;     // quad-uniform load
            for (int p = 0; p < cnt; p += 4) {
                ushort4 nxt = cur;
                if (p + 4 < cnt) nxt = *(const ushort4*)(el + p + 4);
                uint4 v0 = *(const uint4*)&w[(int)cur.x * QST + fbq * 8];
                uint4 v1 = *(const uint4*)&w[(int)cur.y * QST + fbq * 8];
                uint4 v2 = *(const uint4*)&w[(int)cur.z * QST + fbq * 8];
                uint4 v3 = *(const uint4*)&w[(int)cur.w * QST + fbq * 8];
                unsigned d[4][4] = {{v0.x, v0.y, v0.z, v0.w},
                                    {v1.x, v1.y, v1.z, v1.w},
                                    {v2.x, v2.y, v2.z, v2.w},
                                    {v3.x, v3.y, v3.z, v3.w}};
                #pragma unroll
                for (int n = 0; n < 4; ++n) {
                    #pragma unroll
                    for (int k = 0; k < 4; ++k) {
                        DOT2LO(s[2 * k],     d[n][k], one_lo);
                        DOT2LO(s[2 * k + 1], d[n][k], one_hi);
                    }
                }
                cur = nxt;
            }

            // fold into acc + pack NOW: staging = 4 uints
            float dx = di[x];
            #pragma unroll
            for (int k = 0; k < 4; ++k) {
                float zlo = dx * s[2 * k];
                float zhi = dx * s[2 * k + 1];
                acc[x][2 * k]     += zlo;
                acc[x][2 * k + 1] += zhi;
                unsigned lo = (unsigned)f2bf(dx * zlo);
                unsigned hi = (unsigned)f2bf(dx * zhi);
                pst[x][k] = lo | (hi << 16);
            }
        }
        __syncthreads();                 // all reads of old w done
        #pragma unroll
        for (int x = 0; x < 4; ++x) {
            *(uint4*)&w[rnk[x] * QST + fbq * 8] =
                make_uint4(pst[x][0], pst[x][1], pst[x][2], pst[x][3]);
        }
        __syncthreads();                 // new w visible
    }

    // coalesced bf16 write at rank positions (16 B per pass per thread)
    unsigned short* og = accout + (size_t)g * NN * NF + q * 32 + fbq * 8;
    #pragma unroll
    for (int x = 0; x < 4; ++x) {
        int rr = rnk[x];
        uint4 pk;
        pk.x = (unsigned)f2bf(acc[x][0]) | ((unsigned)f2bf(acc[x][1]) << 16);
        pk.y = (unsigned)f2bf(acc[x][2]) | ((unsigned)f2bf(acc[x][3]) << 16);
        pk.z = (unsigned)f2bf(acc[x][4]) | ((unsigned)f2bf(acc[x][5]) << 16);
        pk.w = (unsigned)f2bf(acc[x][6]) | ((unsigned)f2bf(acc[x][7]) << 16);
        *(uint4*)&og[(size_t)rr * NF] = pk;
    }
}

// ---------------------------------------------------------------------------
// MFMA bf16 GEMM: Y[65536,128] = relu(bf16X @ bf16(W) + b), optional fused
// deterministic mean-pool partials. (unchanged: bf16 X input, fuse=1 skips
// the dead Y store.)
// ---------------------------------------------------------------------------
__global__ __launch_bounds__(256, 2) void gemm_bias_relu_kernel(
    const unsigned short* __restrict__ X,   // [BN, NF] bf16
    const float* __restrict__ W,
    const float* __restrict__ b, float* __restrict__ Y,
    float* __restrict__ partial, int fuse)
{
    __shared__ __align__(16) unsigned short Wt[NF * WTS];  // [n][k] bf16
    __shared__ float part[4 * NF];

    int t = threadIdx.x;

    // stage Wt = W^T in bf16
    for (int i = t; i < NF * NF / 4; i += 256) {
        int k = i >> 5;                 // W row
        int n4 = (i & 31) * 4;          // W col group
        float4 wv = ((const float4*)W)[i];
        Wt[(n4 + 0) * WTS + k] = f2bf(wv.x);
        Wt[(n4 + 1) * WTS + k] = f2bf(wv.y);
        Wt[(n4 + 2) * WTS + k] = f2bf(wv.z);
        Wt[(n4 + 3) * WTS + k] = f2bf(wv.w);
    }
    __syncthreads();

    int lane = t & 63;
    int wid  = t >> 6;                  // 0..3
    int quad = lane >> 4;               // 0..3
    int l16  = lane & 15;
    int rowA0 = blockIdx.x * 128 + wid * 32;

    // A fragments: direct bf16 16-B loads (no conversion chain)
    union { uint4 q; sh8 v; } af[2][4];
    #pragma unroll
    for (int m = 0; m < 2; ++m) {
        int r = rowA0 + m * 16 + l16;
        const unsigned short* xr = X + (size_t)r * NF + quad * 8;
        #pragma unroll
        for (int kk = 0; kk < 4; ++kk)
            af[m][kk].q = *(const uint4*)(xr + kk * 32);
    }

    f32x4 acc[2][8];
    #pragma unroll
    for (int m = 0; m < 2; ++m)
        #pragma unroll
        for (int c = 0; c < 8; ++c) acc[m][c] = (f32x4){0.f, 0.f, 0.f, 0.f};

    #pragma unroll
    for (int c = 0; c < 8; ++c) {
        const unsigned short* wb = &Wt[(c * 16 + l16) * WTS + quad * 8];
        #pragma unroll
        for (int kk = 0; kk < 4; ++kk) {
            union { uint4 q; sh8 v; } bf_;
            bf_.q = *(const uint4*)(wb + kk * 32);
            acc[0][c] = __builtin_amdgcn_mfma_f32_16x16x32_bf16(
                af[0][kk].v, bf_.v, acc[0][c], 0, 0, 0);
            acc[1][c] = __builtin_amdgcn_mfma_f32_16x16x32_bf16(
                af[1][kk].v, bf_.v, acc[1][c], 0, 0, 0);
        }
    }

    float psum[8];
    #pragma unroll
    for (int c = 0; c < 8; ++c) psum[c] = 0.0f;

    #pragma unroll
    for (int c = 0; c < 8; ++c) {
        int col = c * 16 + l16;
        float bias = b[col];
        #pragma unroll
        for (int m = 0; m < 2; ++m) {
            #pragma unroll
            for (int reg = 0; reg < 4; ++reg) {
                int r = rowA0 + m * 16 + quad * 4 + reg;
                float v = fmaxf(acc[m][c][reg] + bias, 0.0f);
                if (!fuse) Y[(size_t)r * NF + col] = v;
                psum[c] += v;
            }
        }
    }

    if (fuse) {
        // deterministic cross-quad reduction, then cross-wave LDS tree
        #pragma unroll
        for (int c = 0; c < 8; ++c) {
            float v = psum[c];
            v += __shfl_xor(v, 16);
            v += __shfl_xor(v, 32);
            if (lane < 16) part[wid * NF + c * 16 + lane] = v;
        }
        __syncthreads();
        if (t < NF) {
            float s = part[t] + part[NF + t] + part[2 * NF + t]
                    + part[3 * NF + t];
            partial[(size_t)blockIdx.x * NF + t] = s;
        }
    }
}

// ---------------------------------------------------------------------------
// Readout: per graph, mean-pool from gemm2 partials (4 blocks/graph) + MLP.
// ---------------------------------------------------------------------------
__global__ __launch_bounds__(128) void readout_kernel(
    const float* __restrict__ partial,   // [BN/128][NF]
    const float* __restrict__ Wr1, const float* __restrict__ br1,
    const float* __restrict__ Wr2, const float* __restrict__ br2,
    float* __restrict__ out)
{
    __shared__ float hsh[NF];
    __shared__ float r1[64];

    int g = blockIdx.x;
    int t = threadIdx.x;

    const float* pg = partial + (size_t)g * 4 * NF;
    float s = 0.0f;
    #pragma unroll
    for (int j = 0; j < 4; ++j) s += pg[j * NF + t];
    hsh[t] = s * (1.0f / (float)NN);
    __syncthreads();

    if (t < 64) {
        float a = br1[t];
        #pragma unroll 8
        for (int k = 0; k < NF; ++k) a += hsh[k] * Wr1[k * 64 + t];
        r1[t] = fmaxf(a, 0.0f);
    }
    __syncthreads();

    if (t < 64) {
        float v = r1[t] * Wr2[t];
        #pragma unroll
        for (int off = 32; off; off >>= 1) v += __shfl_down(v, off);
        if (t == 0) out[g] = v + br2[0];
    }
}

// ---------------------------------------------------------------------------
extern "C" void kernel_launch(void* const* d_in, const int* in_sizes, int n_in,
                              void* d_out, int out_size, void* d_ws, size_t ws_size,
                              hipStream_t stream)
{
    const float* X    = (const float*)d_in[0];
    // d_in[1] = batch (unused; nodes already grouped per graph)
    const int*   ei   = (const int*)d_in[2];
    const float* W1   = (const float*)d_in[3];
    const float* b1   = (const float*)d_in[4];
    const float* W2   = (const float*)d_in[5];
    const float* b2   = (const float*)d_in[6];
    const float* Wr1  = (const float*)d_in[7];
    const float* br1  = (const float*)d_in[8];
    const float* Wr2  = (const float*)d_in[9];
    const float* br2  = (const float*)d_in[10];
    float* out = (float*)d_out;

    const int* src = ei;
    const int* dst = ei + NE;

    // workspace layout
    char* ws = (char*)d_ws;
    float*          dinvr   = (float*)(ws);                          // 256 KB
    int*            ocnt    = (int*)(ws + (size_t)256 * 1024);       // 32 KB
    int*            perm    = (int*)(ws + (size_t)512 * 1024);       // 256 KB
    float*          partial = (float*)(ws + (size_t)768 * 1024);     // 256 KB
    unsigned short* ell     = (unsigned short*)(ws + (size_t)1024 * 1024); // 8 MB
    unsigned short* buf0    = (unsigned short*)(ws + (size_t)16384 * 1024); // 16.7 MB bf16
    float*          buf1    = (float*)(ws + (size_t)49152 * 1024);   // 32 MB f32

    // ---- adjacency build: single fused kernel (graph x rank-half)
    build_fused_kernel<<<NB * 2, 1024, 0, stream>>>(src, dst, ell, ocnt,
                                                    dinvr, perm);

    // bf16 w rows (513 * 64 B) = 32,832 B (dsh removed -> registers)
    const size_t LDSSZ = (size_t)(NN + 1) * QST * 2;

    // ---- Layer 1 (X gathered via perm into rank space; accout bf16)
    poly_fused_kernel<<<NB * 4, 512, LDSSZ, stream>>>(X, buf0, ell, ocnt,
                                                      dinvr, perm, 1);
    gemm_bias_relu_kernel<<<BN / 128, 256, 0, stream>>>(buf0, W1, b1, buf1,
                                                        partial, 0);

    // ---- Layer 2 (all rank space, fully coalesced; accout bf16)
    poly_fused_kernel<<<NB * 4, 512, LDSSZ, stream>>>(buf1, buf0, ell, ocnt,
                                                      dinvr, perm, 0);
    gemm_bias_relu_kernel<<<BN / 128, 256, 0, stream>>>(buf0, W2, b2, buf1,
                                                        partial, 1);

    // ---- Readout from partials
    readout_kernel<<<NB, 128, 0, stream>>>(partial, Wr1, br1, Wr2, br2, out);
}